// Round 1
// baseline (1143.479 us; speedup 1.0000x reference)
//
#include <hip/hip_runtime.h>

#define HW 65536
#define CDIM 64

typedef __attribute__((ext_vector_type(8))) short bf16x8;
typedef __attribute__((ext_vector_type(4))) float f32x4;
typedef __attribute__((ext_vector_type(4))) unsigned short u16x4;

__device__ __forceinline__ unsigned short f2bf(float x) {
    union { float f; unsigned u; } v; v.f = x;
    unsigned r = v.u + 0x7fffu + ((v.u >> 16) & 1u);
    return (unsigned short)(r >> 16);
}

// ---------------- Pass 1: projections (fp32 accumulate, bf16 out) ----------------

__global__ __launch_bounds__(256, 2)
void proj_qv_kernel(const float* __restrict__ x,
                    const float* __restrict__ wq, const float* __restrict__ bq,
                    const float* __restrict__ wv, const float* __restrict__ bv,
                    unsigned short* __restrict__ qo, unsigned short* __restrict__ vo) {
    const int t = threadIdx.x;
    const int b = blockIdx.y;
    const int pix = blockIdx.x * 256 + t;
    const float* xp = x + (size_t)b * CDIM * HW + pix;

    float aq[CDIM], av[CDIM];
#pragma unroll
    for (int c = 0; c < CDIM; ++c) { aq[c] = bq[c]; av[c] = bv[c]; }

    for (int i = 0; i < CDIM; ++i) {
        float xv = xp[(size_t)i * HW];
#pragma unroll
        for (int c = 0; c < CDIM; ++c) {
            aq[c] = fmaf(wq[c * CDIM + i], xv, aq[c]);
            av[c] = fmaf(wv[c * CDIM + i], xv, av[c]);
        }
    }
    size_t ob = (size_t)b * CDIM * HW + pix;
#pragma unroll
    for (int c = 0; c < CDIM; ++c) {
        qo[ob + (size_t)c * HW] = f2bf(aq[c]);
        vo[ob + (size_t)c * HW] = f2bf(av[c]);
    }
}

__global__ __launch_bounds__(256, 2)
void proj_k_kernel(const float* __restrict__ x,
                   const float* __restrict__ wk, const float* __restrict__ bk,
                   unsigned short* __restrict__ ko) {
    const int t = threadIdx.x;
    const int nb = blockIdx.y;          // (n*B + b), 0..15
    const int pix = blockIdx.x * 256 + t;
    const float* xp = x + (size_t)nb * CDIM * HW + pix;

    float ak[CDIM];
#pragma unroll
    for (int c = 0; c < CDIM; ++c) ak[c] = bk[c];

    for (int i = 0; i < CDIM; ++i) {
        float xv = xp[(size_t)i * HW];
#pragma unroll
        for (int c = 0; c < CDIM; ++c) ak[c] = fmaf(wk[c * CDIM + i], xv, ak[c]);
    }
    size_t ob = (size_t)nb * CDIM * HW + pix;
#pragma unroll
    for (int c = 0; c < CDIM; ++c) ko[ob + (size_t)c * HW] = f2bf(ak[c]);
}

// ---------------- Pass 1.5: 256x256 bf16 transpose (per slice), 64x64 tiles ----------------

__global__ __launch_bounds__(256)
void transpose_kernel(const unsigned short* __restrict__ src, unsigned short* __restrict__ dst) {
    __shared__ unsigned short T[64 * 72];
    const int t = threadIdx.x;
    const int sl = blockIdx.y;
    const int th = blockIdx.x >> 2, tw = blockIdx.x & 3;

    const unsigned short* s = src + (size_t)sl * HW + th * 64 * 256 + tw * 64;
#pragma unroll
    for (int it = 0; it < 2; ++it) {
        int cc = t + it * 256;          // 512 chunks of 8 elems
        int r = cc >> 3, j = cc & 7;
        *(bf16x8*)&T[r * 72 + j * 8] = *(const bf16x8*)&s[r * 256 + j * 8];
    }
    __syncthreads();
    unsigned short* d = dst + (size_t)sl * HW + tw * 64 * 256 + th * 64;
#pragma unroll
    for (int it = 0; it < 2; ++it) {
        int cc = t + it * 256;
        int w = cc >> 3, j = cc & 7;
        bf16x8 val;
#pragma unroll
        for (int e = 0; e < 8; ++e) val[e] = (short)T[(j * 8 + e) * 72 + w];
        *(bf16x8*)&d[w * 256 + j * 8] = val;
    }
}

// ---------------- Pass 2: fused dual attention per (b,c) ----------------
// LDS: P region 256 rows x 264 elems bf16 (132KB), K-block 256 rows x 40 elems (20KB)
#define PSTRIDE 264
#define KBOFF   67584   // 256*264
#define KBSTRIDE 40

__global__ __launch_bounds__(512, 2)
void attn_kernel(const unsigned short* __restrict__ q,  const unsigned short* __restrict__ qT,
                 const unsigned short* __restrict__ v,  const unsigned short* __restrict__ vT,
                 const unsigned short* __restrict__ k,  const unsigned short* __restrict__ kT,
                 const float* __restrict__ mainx, float* __restrict__ out) {
    __shared__ unsigned short lds[77824]; // 155648 bytes

    const int t = threadIdx.x;
    const int wave = t >> 6, lane = t & 63;
    const int quad = lane >> 4, l16 = lane & 15;
    const int bc = blockIdx.x;

    const unsigned short* Q  = q  + (size_t)bc * HW;
    const unsigned short* QT = qT + (size_t)bc * HW;
    const unsigned short* V  = v  + (size_t)bc * HW;
    const unsigned short* VT = vT + (size_t)bc * HW;

    f32x4 oacc[2][16];
#pragma unroll
    for (int rt = 0; rt < 2; ++rt)
#pragma unroll
        for (int ct = 0; ct < 16; ++ct) oacc[rt][ct] = (f32x4){0.f, 0.f, 0.f, 0.f};

    // cooperative stage of a 256-row x 32-col block (row stride 256 in global) into KB region
    auto stage = [&](const unsigned short* src, int col0) {
#pragma unroll
        for (int it = 0; it < 2; ++it) {
            int cc = t + it * 512;      // 1024 chunks (256 rows x 4)
            int r = cc >> 2, j = cc & 3;
            *(bf16x8*)&lds[KBOFF + r * KBSTRIDE + j * 8] =
                *(const bf16x8*)&src[r * 256 + col0 + j * 8];
        }
    };

    for (int n = 0; n < 4; ++n) {
        const unsigned short* K  = k  + ((size_t)n * 256 + bc) * HW;
        const unsigned short* KT = kT + ((size_t)n * 256 + bc) * HW;

        // ================= TIME attention: S1 = Q K^T, P1 = softmax, out += P1 V =========
        for (int rt = 0; rt < 2; ++rt) {
            f32x4 s[16];
#pragma unroll
            for (int ct = 0; ct < 16; ++ct) s[ct] = (f32x4){0.f, 0.f, 0.f, 0.f};
            const unsigned short* arow = Q + (wave * 32 + rt * 16 + l16) * 256 + quad * 8;
            for (int ks = 0; ks < 8; ++ks) {
                __syncthreads();
                stage(K, ks * 32);
                __syncthreads();
                bf16x8 a = *(const bf16x8*)&arow[ks * 32];
#pragma unroll
                for (int ct = 0; ct < 16; ++ct) {
                    bf16x8 bb = *(const bf16x8*)&lds[KBOFF + (ct * 16 + l16) * KBSTRIDE + quad * 8];
                    s[ct] = __builtin_amdgcn_mfma_f32_16x16x32_bf16(a, bb, s[ct], 0, 0, 0);
                }
            }
            // row softmax (rows: quad*4+r within strip; 16 lanes of a quad share a row)
#pragma unroll
            for (int r = 0; r < 4; ++r) {
                float m = s[0][r];
#pragma unroll
                for (int ct = 1; ct < 16; ++ct) m = fmaxf(m, s[ct][r]);
#pragma unroll
                for (int off = 1; off < 16; off <<= 1) m = fmaxf(m, __shfl_xor(m, off, 64));
                float sum = 0.f;
#pragma unroll
                for (int ct = 0; ct < 16; ++ct) {
                    float e = __expf((s[ct][r] - m) * 0.0625f);
                    s[ct][r] = e; sum += e;
                }
#pragma unroll
                for (int off = 1; off < 16; off <<= 1) sum += __shfl_xor(sum, off, 64);
                float inv = 1.f / sum;
#pragma unroll
                for (int ct = 0; ct < 16; ++ct) s[ct][r] *= inv;
            }
            // write P1 strip, row-major [h][g]
            int hh = wave * 32 + rt * 16 + quad * 4;
#pragma unroll
            for (int ct = 0; ct < 16; ++ct)
#pragma unroll
                for (int r = 0; r < 4; ++r)
                    lds[(hh + r) * PSTRIDE + ct * 16 + l16] = f2bf(s[ct][r]);
        }
        __syncthreads();
        // PV: out += P1 V  (A = own P1 rows from LDS, B = V^T blocks staged)
        for (int gb = 0; gb < 8; ++gb) {
            __syncthreads();
            stage(VT, gb * 32);
            __syncthreads();
#pragma unroll
            for (int rt = 0; rt < 2; ++rt) {
                bf16x8 a = *(const bf16x8*)&lds[(wave * 32 + rt * 16 + l16) * PSTRIDE + gb * 32 + quad * 8];
#pragma unroll
                for (int ct = 0; ct < 16; ++ct) {
                    bf16x8 bb = *(const bf16x8*)&lds[KBOFF + (ct * 16 + l16) * KBSTRIDE + quad * 8];
                    oacc[rt][ct] = __builtin_amdgcn_mfma_f32_16x16x32_bf16(a, bb, oacc[rt][ct], 0, 0, 0);
                }
            }
        }

        // ================= SPACE attention: S2 = Q^T K, P2 = softmax, out += V P2 =======
        for (int rt = 0; rt < 2; ++rt) {
            f32x4 s[16];
#pragma unroll
            for (int ct = 0; ct < 16; ++ct) s[ct] = (f32x4){0.f, 0.f, 0.f, 0.f};
            const unsigned short* arow = QT + (wave * 32 + rt * 16 + l16) * 256 + quad * 8;
            for (int ks = 0; ks < 8; ++ks) {
                __syncthreads();
                stage(KT, ks * 32);
                __syncthreads();
                bf16x8 a = *(const bf16x8*)&arow[ks * 32];
#pragma unroll
                for (int ct = 0; ct < 16; ++ct) {
                    bf16x8 bb = *(const bf16x8*)&lds[KBOFF + (ct * 16 + l16) * KBSTRIDE + quad * 8];
                    s[ct] = __builtin_amdgcn_mfma_f32_16x16x32_bf16(a, bb, s[ct], 0, 0, 0);
                }
            }
#pragma unroll
            for (int r = 0; r < 4; ++r) {
                float m = s[0][r];
#pragma unroll
                for (int ct = 1; ct < 16; ++ct) m = fmaxf(m, s[ct][r]);
#pragma unroll
                for (int off = 1; off < 16; off <<= 1) m = fmaxf(m, __shfl_xor(m, off, 64));
                float sum = 0.f;
#pragma unroll
                for (int ct = 0; ct < 16; ++ct) {
                    float e = __expf((s[ct][r] - m) * 0.0625f);
                    s[ct][r] = e; sum += e;
                }
#pragma unroll
                for (int off = 1; off < 16; off <<= 1) sum += __shfl_xor(sum, off, 64);
                float inv = 1.f / sum;
#pragma unroll
                for (int ct = 0; ct < 16; ++ct) s[ct][r] *= inv;
            }
            // write P2 transposed into LDS as [v][w] (w contiguous) — packed 4-elem writes
            int wbase = wave * 32 + rt * 16 + quad * 4;
#pragma unroll
            for (int ct = 0; ct < 16; ++ct) {
                u16x4 pk;
#pragma unroll
                for (int r = 0; r < 4; ++r) pk[r] = f2bf(s[ct][r]);
                *(u16x4*)&lds[(ct * 16 + l16) * PSTRIDE + wbase] = pk;
            }
        }
        __syncthreads();
        // PV: out += V P2  (A = V rows from global, B = P2^T rows from LDS)
        for (int ks = 0; ks < 8; ++ks) {
#pragma unroll
            for (int rt = 0; rt < 2; ++rt) {
                bf16x8 a = *(const bf16x8*)&V[(wave * 32 + rt * 16 + l16) * 256 + ks * 32 + quad * 8];
#pragma unroll
                for (int ct = 0; ct < 16; ++ct) {
                    bf16x8 bb = *(const bf16x8*)&lds[(ct * 16 + l16) * PSTRIDE + ks * 32 + quad * 8];
                    oacc[rt][ct] = __builtin_amdgcn_mfma_f32_16x16x32_bf16(a, bb, oacc[rt][ct], 0, 0, 0);
                }
            }
        }
        __syncthreads();
    }

    // epilogue: out = main + sum
    const float* mp = mainx + (size_t)bc * HW;
    float* op = out + (size_t)bc * HW;
#pragma unroll
    for (int rt = 0; rt < 2; ++rt)
#pragma unroll
        for (int ct = 0; ct < 16; ++ct)
#pragma unroll
            for (int r = 0; r < 4; ++r) {
                int hh = wave * 32 + rt * 16 + quad * 4 + r;
                int ww = ct * 16 + l16;
                op[hh * 256 + ww] = mp[hh * 256 + ww] + oacc[rt][ct][r];
            }
}

// ---------------- launch ----------------

extern "C" void kernel_launch(void* const* d_in, const int* in_sizes, int n_in,
                              void* d_out, int out_size, void* d_ws, size_t ws_size,
                              hipStream_t stream) {
    const float* mainx  = (const float*)d_in[0];
    const float* assist = (const float*)d_in[1];
    const float* wq = (const float*)d_in[2];
    const float* bq = (const float*)d_in[3];
    const float* wk = (const float*)d_in[4];
    const float* bk = (const float*)d_in[5];
    const float* wv = (const float*)d_in[6];
    const float* bv = (const float*)d_in[7];
    float* outp = (float*)d_out;

    unsigned short* ws = (unsigned short*)d_ws;
    const size_t SLICE = (size_t)16777216;          // B*C*H*W elements
    unsigned short* Qw  = ws;
    unsigned short* QTw = ws + SLICE;
    unsigned short* Vw  = ws + 2 * SLICE;
    unsigned short* VTw = ws + 3 * SLICE;
    unsigned short* Kw  = ws + 4 * SLICE;           // N*B*C*H*W = 4*SLICE
    unsigned short* KTw = ws + 8 * SLICE;
    // total: 12 * SLICE * 2 bytes = 402,653,184 bytes

    proj_qv_kernel<<<dim3(256, 4), 256, 0, stream>>>(mainx, wq, bq, wv, bv, Qw, Vw);
    proj_k_kernel<<<dim3(256, 16), 256, 0, stream>>>(assist, wk, bk, Kw);

    transpose_kernel<<<dim3(16, 256), 256, 0, stream>>>(Qw, QTw);
    transpose_kernel<<<dim3(16, 256), 256, 0, stream>>>(Vw, VTw);
    transpose_kernel<<<dim3(16, 1024), 256, 0, stream>>>(Kw, KTw);

    attn_kernel<<<dim3(256), 512, 0, stream>>>(Qw, QTw, Vw, VTw, Kw, KTw, mainx, outp);
}